// Round 8
// baseline (169.199 us; speedup 1.0000x reference)
//
#include <hip/hip_runtime.h>

// B=4, L=S=2048, H=8, E=D=64.  KM[bh][t][e] = sum_s K[b,s,h,e]*M[s,t] (split
// bf16 hi/lo), then flash attention z = Q*KM/8, causal, online softmax.
// Round 8: attn -> 1024 blocks (every q-tile split into 2 kv-halves; CU slots
// {15-k:h0,15-k:h1,k:h0,k:h1} = 34 tiles, uniform finish), 40KB LDS (single-
// buffer VT with vmcnt(4) gate), 4 blocks/CU, pointer-increment staging,
// bf16 partials + full combine. km/preps unchanged.

typedef short bf16x8 __attribute__((ext_vector_type(8)));
typedef float f32x4 __attribute__((ext_vector_type(4)));
typedef float f32x16 __attribute__((ext_vector_type(16)));
typedef unsigned short u16x8 __attribute__((ext_vector_type(8)));
typedef unsigned int u32x4 __attribute__((ext_vector_type(4)));

typedef __attribute__((address_space(1))) const void gvoid;
typedef __attribute__((address_space(3))) void lvoid;

__device__ __forceinline__ unsigned short f2bf(float x) {
  unsigned int u = __float_as_uint(x);
  u += 0x7FFFu + ((u >> 16) & 1u);
  return (unsigned short)(u >> 16);
}
__device__ __forceinline__ float bf2f(unsigned short h) {
  return __uint_as_float(((unsigned int)h) << 16);
}
// pack two f32 -> (bf16(hi)<<16)|bf16(lo)
__device__ __forceinline__ unsigned int cvtpk(float lo, float hi) {
  unsigned int r;
  asm("v_cvt_pk_bf16_f32 %0, %1, %2" : "=v"(r) : "v"(lo), "v"(hi));
  return r;
}

__device__ __forceinline__ void gload16(const unsigned short* g, unsigned short* l) {
  __builtin_amdgcn_global_load_lds((gvoid*)g, (lvoid*)l, 16, 0, 0);
}

// Stage a [rows][64 bf16] tile (row stride 128B in LDS) from global rows of
// stride gstride. LDS dest LINEAR (global_load_lds rule); XOR swizzle
// byte^=((row&7)<<4) realized by pre-swizzling the global SOURCE address.
template <int NW>
__device__ __forceinline__ void stage_tile(const unsigned short* __restrict__ g,
                                           int gstride, unsigned short* l,
                                           int rows, int tid) {
  const int lane = tid & 63, w = tid >> 6;
  const int nch = rows << 3;  // 16B chunks
  for (int c0 = (w << 6); c0 < nch; c0 += NW * 64) {
    const int c = c0 + lane;
    const int row = c >> 3;
    const int bir = (c & 7) << 4;
    const int sb = bir ^ ((row & 7) << 4);
    gload16(g + (size_t)row * gstride + (sb >> 1), l + (size_t)c0 * 8);
  }
}

// swizzled byte offset inside a [*][64 bf16] tile
__device__ __forceinline__ int swz(int row, int byteInRow) {
  return row * 128 + (byteInRow ^ ((row & 7) << 4));
}

// u16 offset of chunk c inside a [64 rows][gstride] global tile (pre-swizzled)
__device__ __forceinline__ int chunk_off(int c, int gstride) {
  return (c >> 3) * gstride + ((((c & 7) ^ ((c >> 3) & 7))) << 3);
}

// ---------------------------------------------------------------------------
// prep_m: Mt_hi/lo[t][s] = split(M[s][t])
// ---------------------------------------------------------------------------
__global__ __launch_bounds__(256) void prep_m(const float* __restrict__ M,
                                              unsigned short* __restrict__ Mh,
                                              unsigned short* __restrict__ Ml) {
  __shared__ float Ts[64][68];
  const int s0 = blockIdx.x << 6, t0 = blockIdx.y << 6;
  const int tid = threadIdx.x, r = tid >> 2, c0 = (tid & 3) << 4;
  const float* src = M + (size_t)(s0 + r) * 2048 + t0 + c0;
#pragma unroll
  for (int j = 0; j < 4; ++j)
    *(float4*)&Ts[r][c0 + 4 * j] = *(const float4*)(src + 4 * j);
  __syncthreads();
  u16x8 h0, h1, l0v, l1v;
#pragma unroll
  for (int j = 0; j < 8; ++j) {
    float x = Ts[c0 + j][r];
    unsigned short hh = f2bf(x);
    h0[j] = hh; l0v[j] = f2bf(x - bf2f(hh));
  }
#pragma unroll
  for (int j = 8; j < 16; ++j) {
    float x = Ts[c0 + j][r];
    unsigned short hh = f2bf(x);
    h1[j - 8] = hh; l1v[j - 8] = f2bf(x - bf2f(hh));
  }
  const size_t o = (size_t)(t0 + r) * 2048 + s0 + c0;
  *(u16x8*)(Mh + o) = h0; *(u16x8*)(Mh + o + 8) = h1;
  *(u16x8*)(Ml + o) = l0v; *(u16x8*)(Ml + o + 8) = l1v;
}

// ---------------------------------------------------------------------------
// prep_kv: Dst[bh][e][s] = split(src[b,s,h,e]); has_lo=0 -> single plane (V)
// ---------------------------------------------------------------------------
__global__ __launch_bounds__(256) void prep_kv(const float* __restrict__ src4d,
                                               unsigned short* __restrict__ Dh,
                                               unsigned short* __restrict__ Dl,
                                               int has_lo) {
  __shared__ float Ts[64][68];
  const int s0 = blockIdx.x << 6, bh = blockIdx.y;
  const int b = bh >> 3, h = bh & 7;
  const int tid = threadIdx.x, r = tid >> 2, c0 = (tid & 3) << 4;
  const float* src = src4d + ((size_t)(b * 2048 + s0 + r) * 8 + h) * 64 + c0;
#pragma unroll
  for (int j = 0; j < 4; ++j)
    *(float4*)&Ts[r][c0 + 4 * j] = *(const float4*)(src + 4 * j);
  __syncthreads();
  u16x8 h0, h1, l0v, l1v;
#pragma unroll
  for (int j = 0; j < 8; ++j) {
    float x = Ts[c0 + j][r];
    unsigned short hh = f2bf(x);
    h0[j] = hh; l0v[j] = f2bf(x - bf2f(hh));
  }
#pragma unroll
  for (int j = 8; j < 16; ++j) {
    float x = Ts[c0 + j][r];
    unsigned short hh = f2bf(x);
    h1[j - 8] = hh; l1v[j - 8] = f2bf(x - bf2f(hh));
  }
  const size_t o = ((size_t)bh * 64 + r) * 2048 + s0 + c0;
  *(u16x8*)(Dh + o) = h0; *(u16x8*)(Dh + o + 8) = h1;
  if (has_lo) { *(u16x8*)(Dl + o) = l0v; *(u16x8*)(Dl + o + 8) = l1v; }
}

// ---------------------------------------------------------------------------
// km_mfma: KM[bh][t][e] (hi/lo) = sum_s M[s][t]*K[s][e]  (proven v1)
// ---------------------------------------------------------------------------
__global__ __launch_bounds__(256) void km_mfma(
    const unsigned short* __restrict__ Mth, const unsigned short* __restrict__ Mtl,
    const unsigned short* __restrict__ Kth, const unsigned short* __restrict__ Ktl,
    unsigned short* __restrict__ KMh, unsigned short* __restrict__ KMl) {
  __shared__ __attribute__((aligned(16))) unsigned short sm[24576];  // 48 KB
  unsigned short* MtH = sm;
  unsigned short* MtL = sm + 8192;
  unsigned short* KtH = sm + 16384;
  unsigned short* KtL = sm + 20480;
  const int tid = threadIdx.x, lane = tid & 63, w = tid >> 6;
  const int g = lane >> 4, li = lane & 15;
  const int t0 = blockIdx.x << 7;
  const int bh = blockIdx.y;
  const unsigned short* KtHb = Kth + (size_t)bh * 64 * 2048;
  const unsigned short* KtLb = Ktl + (size_t)bh * 64 * 2048;

  f32x4 acc[2][4];
#pragma unroll
  for (int mi = 0; mi < 2; ++mi)
#pragma unroll
    for (int ni = 0; ni < 4; ++ni) acc[mi][ni] = (f32x4){0.f, 0.f, 0.f, 0.f};

  for (int s0 = 0; s0 < 2048; s0 += 64) {
    __syncthreads();
    stage_tile<4>(Mth + (size_t)t0 * 2048 + s0, 2048, MtH, 128, tid);
    stage_tile<4>(Mtl + (size_t)t0 * 2048 + s0, 2048, MtL, 128, tid);
    stage_tile<4>(KtHb + s0, 2048, KtH, 64, tid);
    stage_tile<4>(KtLb + s0, 2048, KtL, 64, tid);
    asm volatile("s_waitcnt vmcnt(0)" ::: "memory");
    __syncthreads();
#pragma unroll
    for (int kk = 0; kk < 2; ++kk) {
      const int kb = (kk * 32 + 8 * g) * 2;
      bf16x8 aH[2], aL[2];
#pragma unroll
      for (int mi = 0; mi < 2; ++mi) {
        const int row = (w << 5) + (mi << 4) + li;
        aH[mi] = *(const bf16x8*)((const char*)MtH + swz(row, kb));
        aL[mi] = *(const bf16x8*)((const char*)MtL + swz(row, kb));
      }
#pragma unroll
      for (int ni = 0; ni < 4; ++ni) {
        const int row = (ni << 4) + li;
        const int off = swz(row, kb);
        const bf16x8 bH = *(const bf16x8*)((const char*)KtH + off);
        const bf16x8 bL = *(const bf16x8*)((const char*)KtL + off);
#pragma unroll
        for (int mi = 0; mi < 2; ++mi) {
          acc[mi][ni] = __builtin_amdgcn_mfma_f32_16x16x32_bf16(aH[mi], bH, acc[mi][ni], 0, 0, 0);
          acc[mi][ni] = __builtin_amdgcn_mfma_f32_16x16x32_bf16(aH[mi], bL, acc[mi][ni], 0, 0, 0);
          acc[mi][ni] = __builtin_amdgcn_mfma_f32_16x16x32_bf16(aL[mi], bH, acc[mi][ni], 0, 0, 0);
        }
      }
    }
  }
  const size_t base = (size_t)bh * 2048 * 64;
#pragma unroll
  for (int mi = 0; mi < 2; ++mi)
#pragma unroll
    for (int r = 0; r < 4; ++r) {
      const int trow = t0 + (w << 5) + (mi << 4) + (g << 2) + r;
#pragma unroll
      for (int ni = 0; ni < 4; ++ni) {
        const float x = acc[mi][ni][r];
        const unsigned short hh = f2bf(x);
        const size_t idx = base + (size_t)trow * 64 + (ni << 4) + li;
        KMh[idx] = hh;
        KMl[idx] = f2bf(x - bf2f(hh));
      }
    }
}

// ---------------------------------------------------------------------------
// attn32: 1024 blocks, 4/CU. bid -> x=bid&7 (XCD), n=bid>>3, slot=n>>5,
// j=n&31, bh=(x<<2)|(j&3), k=j>>2, hf=slot&1, lt = slot<2 ? 15-k : k.
// Each block does one kv-HALF of q-tile lt: half=lt+1 tiles. Per CU slots:
// (16-k)+(16-k)+(k+1)+(k+1) = 34 tiles, uniform finish. LDS 40KB: K double-
// buffered (2x16KB), VT single (8KB, staged at iter top, vmcnt(4) before PV).
// All outputs partial: bf16 Opart + fp32 (m, lsum); combine merges.
// ---------------------------------------------------------------------------
__global__ __launch_bounds__(256, 4) void attn32(
    const float* __restrict__ Q, const unsigned short* __restrict__ KMh,
    const unsigned short* __restrict__ KMl, const unsigned short* __restrict__ Vt,
    unsigned short* __restrict__ Opart, float* __restrict__ Ml) {
  // LDS u16 map: kbuf0 KH 0..4095 KL 4096..8191 | kbuf1 8192..16383 | VT 16384..20479
  __shared__ __attribute__((aligned(16))) unsigned short sm[20480];
  const int tid = threadIdx.x, lane = tid & 63, w = tid >> 6;
  const int g2 = lane >> 5, li5 = lane & 31;

  const int bid = (int)blockIdx.x;
  const int x = bid & 7, n = bid >> 3;
  const int slot = n >> 5, j = n & 31;
  const int bh = (x << 2) | (j & 3);
  const int k = j >> 2;
  const int hf = slot & 1;
  const int lt = (slot < 2) ? (15 - k) : k;
  const int half = lt + 1;
  const int jt0 = hf * half;
  const int jtEnd = jt0 + half - 1;
  const int b = bh >> 3, h = bh & 7;
  const int l0 = lt << 7;
  const int qg = l0 + (w << 5) + li5;
  const int rloc = (w << 5) + li5;

  // per-thread staging offsets (chunks c0=tid, c1=tid+256 of a 64x64 tile)
  const int c0 = tid, c1 = tid + 256;
  const int ko0 = chunk_off(c0, 64), ko1 = chunk_off(c1, 64);
  const int vo0 = chunk_off(c0, 2048), vo1 = chunk_off(c1, 2048);
  const int ld0 = c0 << 3, ld1 = c1 << 3;
  unsigned short* VTl = sm + 16384;

  // Q fragments (hi/lo) in registers, pre-scaled by 0.125*log2(e).
  const float SC2 = 0.18033688011112042f;
  bf16x8 qh[4], ql[4];
  {
    const float* qsrc = Q + (((size_t)(b * 2048 + qg) * 8 + h) << 6) + (g2 << 3);
#pragma unroll
    for (int kki = 0; kki < 4; ++kki) {
      const float4 v0 = *(const float4*)(qsrc + 16 * kki);
      const float4 v1 = *(const float4*)(qsrc + 16 * kki + 4);
      const float xs[8] = {v0.x, v0.y, v0.z, v0.w, v1.x, v1.y, v1.z, v1.w};
#pragma unroll
      for (int jj = 0; jj < 8; ++jj) {
        const float xv = xs[jj] * SC2;
        const unsigned short hh = f2bf(xv);
        qh[kki][jj] = (short)hh;
        ql[kki][jj] = (short)f2bf(xv - bf2f(hh));
      }
    }
  }

  f32x16 o0 = {0,0,0,0,0,0,0,0,0,0,0,0,0,0,0,0};
  f32x16 o1 = {0,0,0,0,0,0,0,0,0,0,0,0,0,0,0,0};
  f32x16 lsacc = {0,0,0,0,0,0,0,0,0,0,0,0,0,0,0,0};
  float m2 = -1e30f;
  bf16x8 ones;
#pragma unroll
  for (int jj = 0; jj < 8; ++jj) ones[jj] = (short)0x3F80;  // bf16 1.0

  const unsigned short* khsrc = KMh + (size_t)bh * 2048 * 64 + (size_t)jt0 * 4096;
  const unsigned short* klsrc = KMl + (size_t)bh * 2048 * 64 + (size_t)jt0 * 4096;
  const unsigned short* vsrc = Vt + (size_t)bh * 64 * 2048 + jt0 * 64;

  const int jtmax_w = 2 * lt + (w >> 1);

  // prologue: stage K(jt0) into buf jt0&1
  {
    unsigned short* kb = sm + ((jt0 & 1) << 13);
    gload16(khsrc + ko0, kb + ld0);
    gload16(khsrc + ko1, kb + ld1);
    gload16(klsrc + ko0, kb + 4096 + ld0);
    gload16(klsrc + ko1, kb + 4096 + ld1);
  }
  khsrc += 4096; klsrc += 4096;
  asm volatile("s_waitcnt vmcnt(0)" ::: "memory");
  __builtin_amdgcn_s_barrier();
  __builtin_amdgcn_sched_barrier(0);

  for (int jt = jt0; jt <= jtEnd; ++jt) {
    // stage VT(jt) [2 loads], then K(jt+1) [4 loads] into the other K buffer
    gload16(vsrc + vo0, VTl + ld0);
    gload16(vsrc + vo1, VTl + ld1);
    {
      unsigned short* kb = sm + (((jt + 1) & 1) << 13);
      gload16(khsrc + ko0, kb + ld0);
      gload16(khsrc + ko1, kb + ld1);
      gload16(klsrc + ko0, kb + 4096 + ld0);
      gload16(klsrc + ko1, kb + 4096 + ld1);
    }
    khsrc += 4096; klsrc += 4096; vsrc += 64;

    const bool act = (jt <= jtmax_w);
    bf16x8 pf[4];
    if (act) {
      const unsigned short* KH = sm + ((jt & 1) << 13);
      const unsigned short* KL = KH + 4096;

      // z = KM * Q : A = KM[t][e] rows (2 t-frags), B = Q regs (pre-scaled)
      f32x16 z0 = {0,0,0,0,0,0,0,0,0,0,0,0,0,0,0,0};
      f32x16 z1 = {0,0,0,0,0,0,0,0,0,0,0,0,0,0,0,0};
      __builtin_amdgcn_s_setprio(1);
#pragma unroll
      for (int kki = 0; kki < 4; ++kki) {
        const int cb = 32 * kki + 16 * g2;
        const bf16x8 a0h = *(const bf16x8*)((const char*)KH + swz(li5, cb));
        const bf16x8 a0l = *(const bf16x8*)((const char*)KL + swz(li5, cb));
        const bf16x8 a1h = *(const bf16x8*)((const char*)KH + swz(32 + li5, cb));
        const bf16x8 a1l = *(const bf16x8*)((const char*)KL + swz(32 + li5, cb));
        z0 = __builtin_amdgcn_mfma_f32_32x32x16_bf16(a0h, qh[kki], z0, 0, 0, 0);
        z0 = __builtin_amdgcn_mfma_f32_32x32x16_bf16(a0h, ql[kki], z0, 0, 0, 0);
        z0 = __builtin_amdgcn_mfma_f32_32x32x16_bf16(a0l, qh[kki], z0, 0, 0, 0);
        z1 = __builtin_amdgcn_mfma_f32_32x32x16_bf16(a1h, qh[kki], z1, 0, 0, 0);
        z1 = __builtin_amdgcn_mfma_f32_32x32x16_bf16(a1h, ql[kki], z1, 0, 0, 0);
        z1 = __builtin_amdgcn_mfma_f32_32x32x16_bf16(a1l, qh[kki], z1, 0, 0, 0);
      }
      __builtin_amdgcn_s_setprio(0);

      // causal mask (z pre-scaled; select only)
      const bool needmask = (jt * 64 + 63 > l0 + (w << 5));
      if (needmask) {
        const int thr = qg - jt * 64;  // mask if t_loc > thr
#pragma unroll
        for (int rr = 0; rr < 16; ++rr) {
          const int tl = (g2 << 2) + ((rr >> 2) << 3) + (rr & 3);
          if (tl > thr) z0[rr] = -1e30f;
          if (tl + 32 > thr) z1[rr] = -1e30f;
        }
      }

      // running max with deferred rescale (THR=11 in log2 domain)
      float t16[16];
#pragma unroll
      for (int rr = 0; rr < 16; ++rr) t16[rr] = fmaxf(z0[rr], z1[rr]);
#pragma unroll
      for (int s = 8; s; s >>= 1)
#pragma unroll
        for (int rr = 0; rr < 8; ++rr)
          if (rr < s) t16[rr] = fmaxf(t16[rr], t16[rr + s]);
      const float mx = fmaxf(t16[0], __shfl_xor(t16[0], 32));
      if (__any(mx > m2 + 11.0f)) {
        const float m2n = fmaxf(m2, mx);
        const float fs = exp2f(m2 - m2n);
        m2 = m2n;
#pragma unroll
        for (int rr = 0; rr < 16; ++rr) { o0[rr] *= fs; o1[rr] *= fs; }
        lsacc[0] *= fs;
      }

      // P = exp2(z - m2), packed to bf16 pairs in-register
      float pv0[16], pv1[16];
#pragma unroll
      for (int rr = 0; rr < 16; ++rr) {
        pv0[rr] = exp2f(z0[rr] - m2);
        pv1[rr] = exp2f(z1[rr] - m2);
      }
      unsigned int W0[8], W1[8];
#pragma unroll
      for (int i = 0; i < 8; ++i) {
        W0[i] = cvtpk(pv0[2 * i], pv0[2 * i + 1]);
        W1[i] = cvtpk(pv1[2 * i], pv1[2 * i + 1]);
      }
      asm volatile("v_permlane32_swap_b32 %0, %1" : "+v"(W0[0]), "+v"(W0[2]));
      asm volatile("v_permlane32_swap_b32 %0, %1" : "+v"(W0[1]), "+v"(W0[3]));
      asm volatile("v_permlane32_swap_b32 %0, %1" : "+v"(W0[4]), "+v"(W0[6]));
      asm volatile("v_permlane32_swap_b32 %0, %1" : "+v"(W0[5]), "+v"(W0[7]));
      asm volatile("v_permlane32_swap_b32 %0, %1" : "+v"(W1[0]), "+v"(W1[2]));
      asm volatile("v_permlane32_swap_b32 %0, %1" : "+v"(W1[1]), "+v"(W1[3]));
      asm volatile("v_permlane32_swap_b32 %0, %1" : "+v"(W1[4]), "+v"(W1[6]));
      asm volatile("v_permlane32_swap_b32 %0, %1" : "+v"(W1[5]), "+v"(W1[7]));
      {
        u32x4 f0 = {W0[0], W0[1], W0[2], W0[3]};
        u32x4 f1 = {W0[4], W0[5], W0[6], W0[7]};
        u32x4 f2 = {W1[0], W1[1], W1[2], W1[3]};
        u32x4 f3 = {W1[4], W1[5], W1[6], W1[7]};
        pf[0] = __builtin_bit_cast(bf16x8, f0);
        pf[1] = __builtin_bit_cast(bf16x8, f1);
        pf[2] = __builtin_bit_cast(bf16x8, f2);
        pf[3] = __builtin_bit_cast(bf16x8, f3);
      }
    }

    // VT(jt) ready gate: this wave's 2 VT loads are the oldest of 6.
    asm volatile("s_waitcnt vmcnt(4)" ::: "memory");
    __builtin_amdgcn_s_barrier();
    __builtin_amdgcn_sched_barrier(0);

    if (act) {
      // O += V^T * P ; lsum += ones * P   (P from registers)
      __builtin_amdgcn_s_setprio(1);
#pragma unroll
      for (int kki = 0; kki < 4; ++kki) {
        const int cb = 32 * kki + 16 * g2;
        const bf16x8 v0f = *(const bf16x8*)((const char*)VTl + swz(li5, cb));
        const bf16x8 v1f = *(const bf16x8*)((const char*)VTl + swz(32 + li5, cb));
        o0 = __builtin_amdgcn_mfma_f32_32x32x16_bf16(v0f, pf[kki], o0, 0, 0, 0);
        o1 = __builtin_amdgcn_mfma_f32_32x32x16_bf16(v1f, pf[kki], o1, 0, 0, 0);
        lsacc = __builtin_amdgcn_mfma_f32_32x32x16_bf16(ones, pf[kki], lsacc, 0, 0, 0);
      }
      __builtin_amdgcn_s_setprio(0);
    }

    // drain K(jt+1) (in flight across the whole iter), then barrier.
    asm volatile("s_waitcnt vmcnt(0)" ::: "memory");
    __builtin_amdgcn_s_barrier();
    __builtin_amdgcn_sched_barrier(0);
  }

  // epilogue: bf16 partial O (unnormalized) + fp32 (m2, lsum)
  const size_t pidx = (((size_t)bh * 16 + lt) << 7) + rloc;
  unsigned short* op = Opart + (size_t)hf * 4194304 + pidx * 64;
#pragma unroll
  for (int r2 = 0; r2 < 4; ++r2) {
    const int doff = (g2 << 2) + (r2 << 3);
    uint2 pa, pb;
    pa.x = cvtpk(o0[4 * r2], o0[4 * r2 + 1]);
    pa.y = cvtpk(o0[4 * r2 + 2], o0[4 * r2 + 3]);
    *(uint2*)(op + doff) = pa;
    pb.x = cvtpk(o1[4 * r2], o1[4 * r2 + 1]);
    pb.y = cvtpk(o1[4 * r2 + 2], o1[4 * r2 + 3]);
    *(uint2*)(op + 32 + doff) = pb;
  }
  float* mlp = Ml + (((size_t)hf * 65536) + pidx) * 2;
  mlp[0] = m2;
  mlp[1] = lsacc[0];
}

// ---------------------------------------------------------------------------
// attn_combine: merge the two kv-half partials for ALL (bh, lt) q-tiles.
// 2048 blocks x 256 threads; 8 threads per row (8 d each).
// ---------------------------------------------------------------------------
__global__ __launch_bounds__(256) void attn_combine(
    const unsigned short* __restrict__ Opart, const float* __restrict__ Ml,
    float* __restrict__ Out) {
  const int tid = threadIdx.x;
  const int rowg = (int)blockIdx.x * 32 + (tid >> 3);
  const int d0 = (tid & 7) << 3;
  const int r = rowg & 127;
  const int lt = (rowg >> 7) & 15;
  const int bh = rowg >> 11;
  const int b = bh >> 3, h = bh & 7;
  const size_t pidx = (((size_t)bh * 16 + lt) << 7) + r;
  const size_t HOFF = 4194304;   // u16 per hf slot
  const size_t MOFF = 131072;    // floats per hf slot
  const float m0 = Ml[pidx * 2], ls0 = Ml[pidx * 2 + 1];
  const float m1 = Ml[MOFF + pidx * 2], ls1 = Ml[MOFF + pidx * 2 + 1];
  const float mm = fmaxf(m0, m1);
  const float w0 = exp2f(m0 - mm), w1 = exp2f(m1 - mm);
  const float inv = 1.f / (ls0 * w0 + ls1 * w1);
  const u16x8 A = *(const u16x8*)(Opart + pidx * 64 + d0);
  const u16x8 Bv = *(const u16x8*)(Opart + HOFF + pidx * 64 + d0);
  float res[8];
#pragma unroll
  for (int jj = 0; jj < 8; ++jj)
    res[jj] = (bf2f(A[jj]) * w0 + bf2f(Bv[jj]) * w1) * inv;
  const int qg = (lt << 7) + r;
  float* o = Out + (((size_t)(b * 2048 + qg) * 8 + h) << 6) + d0;
  *(float4*)o = make_float4(res[0], res[1], res[2], res[3]);
  *(float4*)(o + 4) = make_float4(res[4], res[5], res[6], res[7]);
}

extern "C" void kernel_launch(void* const* d_in, const int* in_sizes, int n_in,
                              void* d_out, int out_size, void* d_ws, size_t ws_size,
                              hipStream_t stream) {
  const float* Q = (const float*)d_in[0];
  const float* K = (const float*)d_in[1];
  const float* V = (const float*)d_in[2];
  const float* M = (const float*)d_in[3];
  float* Out = (float*)d_out;
  char* ws = (char*)d_ws;
  const size_t MB = 1u << 20;
  unsigned short* Mth = (unsigned short*)(ws);            // [2048 t][2048 s]
  unsigned short* Mtl = (unsigned short*)(ws + 8 * MB);
  unsigned short* Kth = (unsigned short*)(ws + 16 * MB);  // [32 bh][64 e][2048 s]
  unsigned short* Ktl = (unsigned short*)(ws + 24 * MB);
  unsigned short* Vts = (unsigned short*)(ws + 32 * MB);  // [32 bh][64 d][2048 s]
  unsigned short* KMh = (unsigned short*)(ws + 40 * MB);  // [32 bh][2048 t][64 e]
  unsigned short* KMl = (unsigned short*)(ws + 48 * MB);
  // attn partials overlay the (dead after km) M/K staging regions:
  unsigned short* Opart = (unsigned short*)(ws);          // 2 x 8MB bf16
  float* Mlp = (float*)(ws + 16 * MB);                    // 1 MB fp32

  prep_m<<<dim3(32, 32), 256, 0, stream>>>(M, Mth, Mtl);
  prep_kv<<<dim3(32, 32), 256, 0, stream>>>(K, Kth, Ktl, 1);
  prep_kv<<<dim3(32, 32), 256, 0, stream>>>(V, Vts, (unsigned short*)nullptr, 0);
  km_mfma<<<dim3(16, 32), 256, 0, stream>>>(Mth, Mtl, Kth, Ktl, KMh, KMl);
  attn32<<<dim3(1024), 256, 0, stream>>>(Q, KMh, KMl, Vts, Opart, Mlp);
  attn_combine<<<dim3(2048), 256, 0, stream>>>(Opart, Mlp, Out);
}